// Round 3
// baseline (17043.875 us; speedup 1.0000x reference)
//
#include <hip/hip_runtime.h>
#include <cstdint>
#include <cstddef>

typedef unsigned short u16;
typedef __attribute__((ext_vector_type(4))) float f32x4;
typedef __attribute__((ext_vector_type(8))) short s16x8;

#define T_STEPS 512
#define OUT_MAIN 16777216   // 512*64*512
#define HSLOT 65536         // 8 groups * 16 rows * 512 elements per parity slot

// ---------- bf16 split helpers (bit-level RNE) ----------
static __device__ __forceinline__ u16 f2bf(float f) {
  unsigned u = __builtin_bit_cast(unsigned, f);
  unsigned r = u + 0x7FFFu + ((u >> 16) & 1u);
  return (u16)(r >> 16);
}
static __device__ __forceinline__ float bf2f(u16 h) {
  unsigned u = ((unsigned)h) << 16;
  return __builtin_bit_cast(float, u);
}

// ---------- init: full W transpose+split [2048][1024], h0/c0 staging, flags ----------
__global__ void init_k(const float* __restrict__ W, const float* __restrict__ h0,
                       const float* __restrict__ c0,
                       u16* __restrict__ wthi, u16* __restrict__ wtlo,
                       u16* __restrict__ hbhi, u16* __restrict__ hblo,
                       float* __restrict__ cws, unsigned* __restrict__ flags) {
  const int NW = 1024 * 2048;  // full W (Wx rows 0..511, Wh rows 512..1023)
  const int NH = 64 * 512;
  const int total = NW + 3 * NH + 256;
  for (int idx = blockIdx.x * blockDim.x + threadIdx.x; idx < total;
       idx += gridDim.x * blockDim.x) {
    if (idx < NW) {
      int k = idx >> 11;          // row of W (0..1023)
      int c = idx & 2047;         // gate column
      float wv = W[idx];
      u16 hi = f2bf(wv);
      wthi[(size_t)c * 1024 + k] = hi;
      wtlo[(size_t)c * 1024 + k] = f2bf(wv - bf2f(hi));
    } else if (idx < NW + NH) {
      int r = idx - NW; int b = r >> 9; int k = r & 511;
      int g = b >> 3, rr = b & 7;
      float v = h0[r];
      u16 hi = f2bf(v);
      int pos = (g * 16 + rr) * 512 + k;   // parity slot 0 (t=0 reads slot 0)
      hbhi[pos] = hi;
      hblo[pos] = f2bf(v - bf2f(hi));
    } else if (idx < NW + 2 * NH) {
      int r = idx - NW - NH;
      cws[r] = c0[r];
    } else if (idx < NW + 3 * NH) {
      // zero-pad rows 8..15 of both parity slots (MFMA M=16 padding);
      // rec_k never writes padding rows, so this survives the whole call
      int r = idx - NW - 2 * NH;
      int g = r >> 12;
      int rem = r & 4095;
      int row = 8 + (rem >> 9);
      int k = rem & 511;
      int pos = (g * 16 + row) * 512 + k;
      hbhi[pos] = 0; hblo[pos] = 0;
      hbhi[HSLOT + pos] = 0; hblo[HSLOT + pos] = 0;
    } else {
      flags[idx - NW - 3 * NH] = 0u;   // re-armed every call (d_ws is re-poisoned)
    }
  }
}

// ---------- x chunk -> bf16 hi/lo ----------
__global__ void convx_k(const float* __restrict__ x, u16* __restrict__ hi,
                        u16* __restrict__ lo, int n4) {
  for (int i = blockIdx.x * blockDim.x + threadIdx.x; i < n4;
       i += gridDim.x * blockDim.x) {
    float4 v = ((const float4*)x)[i];
    ushort4 h, l2;
    h.x = f2bf(v.x); l2.x = f2bf(v.x - bf2f(h.x));
    h.y = f2bf(v.y); l2.y = f2bf(v.y - bf2f(h.y));
    h.z = f2bf(v.z); l2.z = f2bf(v.z - bf2f(h.z));
    h.w = f2bf(v.w); l2.w = f2bf(v.w - bf2f(h.w));
    ((ushort4*)hi)[i] = h;
    ((ushort4*)lo)[i] = l2;
  }
}

// ---------- G = x@Wx + b : 128x128 tile, 4 waves, 3-term bf16-split MFMA ----------
__global__ void __launch_bounds__(256, 2)
gemm_k(const u16* __restrict__ xhi, const u16* __restrict__ xlo,
       const u16* __restrict__ wthi, const u16* __restrict__ wtlo,
       const float* __restrict__ bias, float* __restrict__ Gout) {
  __shared__ u16 Ah[4096], Al[4096], Bh[4096], Bl[4096];   // [128][32] each
  const int tid = threadIdx.x;
  const int nb = blockIdx.x & 15;
  const int mb = blockIdx.x >> 4;
  const int w = tid >> 6, l = tid & 63;
  const int wm = w >> 1, wn = w & 1;
  const int lr = l & 15, lq = l >> 4;

  const int pos0 = tid, pos1 = tid + 256;
  const int row0 = pos0 >> 2, row1 = pos1 >> 2;
  const int cc = (tid & 3) * 8;
  const size_t aOff0 = (size_t)(mb * 128 + row0) * 512 + cc;
  const size_t aOff1 = (size_t)(mb * 128 + row1) * 512 + cc;
  const size_t bOff0 = (size_t)(nb * 128 + row0) * 1024 + cc;
  const size_t bOff1 = (size_t)(nb * 128 + row1) * 1024 + cc;

  float bv[4];
  #pragma unroll
  for (int n = 0; n < 4; ++n) bv[n] = bias[nb * 128 + wn * 64 + n * 16 + lr];

  f32x4 acc[4][4] = {};
  s16x8 rA0, rA1, rAl0, rAl1, rB0, rB1, rBl0, rBl1;
  rA0  = *(const s16x8*)(xhi  + aOff0);
  rA1  = *(const s16x8*)(xhi  + aOff1);
  rAl0 = *(const s16x8*)(xlo  + aOff0);
  rAl1 = *(const s16x8*)(xlo  + aOff1);
  rB0  = *(const s16x8*)(wthi + bOff0);
  rB1  = *(const s16x8*)(wthi + bOff1);
  rBl0 = *(const s16x8*)(wtlo + bOff0);
  rBl1 = *(const s16x8*)(wtlo + bOff1);

  for (int kt = 0; kt < 16; ++kt) {
    *(s16x8*)&Ah[pos0 * 8] = rA0;  *(s16x8*)&Ah[pos1 * 8] = rA1;
    *(s16x8*)&Al[pos0 * 8] = rAl0; *(s16x8*)&Al[pos1 * 8] = rAl1;
    *(s16x8*)&Bh[pos0 * 8] = rB0;  *(s16x8*)&Bh[pos1 * 8] = rB1;
    *(s16x8*)&Bl[pos0 * 8] = rBl0; *(s16x8*)&Bl[pos1 * 8] = rBl1;
    __syncthreads();
    if (kt < 15) {
      const int k0 = (kt + 1) * 32;
      rA0  = *(const s16x8*)(xhi  + aOff0 + k0);
      rA1  = *(const s16x8*)(xhi  + aOff1 + k0);
      rAl0 = *(const s16x8*)(xlo  + aOff0 + k0);
      rAl1 = *(const s16x8*)(xlo  + aOff1 + k0);
      rB0  = *(const s16x8*)(wthi + bOff0 + k0);
      rB1  = *(const s16x8*)(wthi + bOff1 + k0);
      rBl0 = *(const s16x8*)(wtlo + bOff0 + k0);
      rBl1 = *(const s16x8*)(wtlo + bOff1 + k0);
    }
    s16x8 fAh[4], fAl[4], fBh[4], fBl[4];
    #pragma unroll
    for (int mm = 0; mm < 4; ++mm) {
      const int rrow = wm * 64 + mm * 16 + lr;
      fAh[mm] = *(const s16x8*)&Ah[rrow * 32 + lq * 8];
      fAl[mm] = *(const s16x8*)&Al[rrow * 32 + lq * 8];
    }
    #pragma unroll
    for (int nn = 0; nn < 4; ++nn) {
      const int crow = wn * 64 + nn * 16 + lr;
      fBh[nn] = *(const s16x8*)&Bh[crow * 32 + lq * 8];
      fBl[nn] = *(const s16x8*)&Bl[crow * 32 + lq * 8];
    }
    #pragma unroll
    for (int mm = 0; mm < 4; ++mm)
      #pragma unroll
      for (int nn = 0; nn < 4; ++nn) {
        acc[mm][nn] = __builtin_amdgcn_mfma_f32_16x16x32_bf16(fAh[mm], fBh[nn], acc[mm][nn], 0, 0, 0);
        acc[mm][nn] = __builtin_amdgcn_mfma_f32_16x16x32_bf16(fAh[mm], fBl[nn], acc[mm][nn], 0, 0, 0);
        acc[mm][nn] = __builtin_amdgcn_mfma_f32_16x16x32_bf16(fAl[mm], fBh[nn], acc[mm][nn], 0, 0, 0);
      }
    __syncthreads();
  }
  #pragma unroll
  for (int mm = 0; mm < 4; ++mm)
    #pragma unroll
    for (int nn = 0; nn < 4; ++nn)
      #pragma unroll
      for (int i = 0; i < 4; ++i) {
        const int row = mb * 128 + wm * 64 + mm * 16 + lq * 4 + i;
        const int col = nb * 128 + wn * 64 + nn * 16 + lr;
        Gout[(size_t)row * 2048 + col] = acc[mm][nn][i] + bv[nn];
      }
}

// ---------- recurrence v2: flag-vector barrier, 4 waves (1 gate each, full K),
//            wave-0 elementwise with c in registers ----------
__global__ void __launch_bounds__(256, 1)
rec_k(const u16* __restrict__ wthi, const u16* __restrict__ wtlo,
      const float* __restrict__ Gbuf,
      u16* __restrict__ hbhi, u16* __restrict__ hblo,
      float* __restrict__ cws, float* __restrict__ out,
      unsigned* __restrict__ flags, int t0, int Tc) {
  const int g = blockIdx.x & 7;        // group (XCD heuristic: consecutive ids round-robin XCDs)
  const int m = blockIdx.x >> 3;       // member 0..31: owns hidden units [16m,16m+16)
  const int tid = threadIdx.x;
  const int w = tid >> 6;              // wave = gate index 0..3
  const int l = tid & 63;
  const int lr = l & 15, lq = l >> 4;  // lq 0..3

  __shared__ float gl[8][64];          // [batch][gate*16 + unit]

  // --- Wh^T fragments in registers: wave w = gate w, full K=512 (16 kt) ---
  s16x8 bhi[16], blo[16];
  {
    const size_t wbase = (size_t)(w * 512 + m * 16 + lr) * 1024 + 512 + (size_t)lq * 8;
    #pragma unroll
    for (int kt = 0; kt < 16; ++kt) {
      bhi[kt] = *(const s16x8*)(wthi + wbase + kt * 32);
      blo[kt] = *(const s16x8*)(wtlo + wbase + kt * 32);
    }
  }
  // wave-0 elementwise assignment: lane l -> batch b0 (0..7), units jj, jj+1
  const int b0 = l >> 3;
  const int jj = (l & 7) * 2;
  float c0r = 0.f, c1r = 0.f;
  if (w == 0) {
    const float* cp = cws + (size_t)(g * 8 + b0) * 512 + m * 16 + jj;
    c0r = cp[0]; c1r = cp[1];
  }
  unsigned* gf = flags + g * 32;

  for (int tl = 0; tl < Tc; ++tl) {
    const int t = t0 + tl;
    // issue x-gate loads early (race-free data; hides HBM latency under the spin)
    float2 gv0, gv1, gv2, gv3;
    if (w == 0) {
      const float* gp = Gbuf + ((size_t)tl * 64 + g * 8 + b0) * 2048 + m * 16 + jj;
      gv0 = *(const float2*)(gp);
      gv1 = *(const float2*)(gp + 512);
      gv2 = *(const float2*)(gp + 1024);
      gv3 = *(const float2*)(gp + 1536);
    }
    // parallel flag-vector barrier: every wave polls all 32 member flags (read-only,
    // no RMW serialization); release side is a single atomic store per block
    {
      int ok;
      do {
        unsigned v = __hip_atomic_load(&gf[l & 31], __ATOMIC_ACQUIRE,
                                       __HIP_MEMORY_SCOPE_AGENT);
        ok = __all((int)(v >= (unsigned)t));
        if (!ok) __builtin_amdgcn_s_sleep(1);
      } while (!ok);
    }
    // A fragments (h hi/lo) from parity slot t&1
    const size_t hbOff = (size_t)((t & 1) * HSLOT) + (size_t)(g * 16 + lr) * 512 + lq * 8;
    f32x4 acc[4] = {};
    #pragma unroll
    for (int q = 0; q < 4; ++q) {
      s16x8 ah[4], al[4];
      #pragma unroll
      for (int j = 0; j < 4; ++j) {
        ah[j] = *(const s16x8*)(hbhi + hbOff + (q * 4 + j) * 32);
        al[j] = *(const s16x8*)(hblo + hbOff + (q * 4 + j) * 32);
      }
      #pragma unroll
      for (int j = 0; j < 4; ++j) {
        const int kt = q * 4 + j;
        acc[j] = __builtin_amdgcn_mfma_f32_16x16x32_bf16(ah[j], bhi[kt], acc[j], 0, 0, 0);
        acc[j] = __builtin_amdgcn_mfma_f32_16x16x32_bf16(ah[j], blo[kt], acc[j], 0, 0, 0);
        acc[j] = __builtin_amdgcn_mfma_f32_16x16x32_bf16(al[j], bhi[kt], acc[j], 0, 0, 0);
      }
    }
    const f32x4 accT = (acc[0] + acc[1]) + (acc[2] + acc[3]);
    if (l < 32) {
      #pragma unroll
      for (int i = 0; i < 4; ++i)
        gl[(l >> 4) * 4 + i][w * 16 + lr] = accT[i];
    }
    __syncthreads();
    if (w == 0) {
      const float* glr = &gl[b0][0];
      float fg0 = glr[jj]      + gv0.x, fg1 = glr[jj + 1]  + gv0.y;
      float ig0 = glr[16 + jj] + gv1.x, ig1 = glr[17 + jj] + gv1.y;
      float cg0 = glr[32 + jj] + gv2.x, cg1 = glr[33 + jj] + gv2.y;
      float og0 = glr[48 + jj] + gv3.x, og1 = glr[49 + jj] + gv3.y;
      float fs0 = 1.f / (1.f + __expf(-fg0)), fs1 = 1.f / (1.f + __expf(-fg1));
      float is0 = 1.f / (1.f + __expf(-ig0)), is1 = 1.f / (1.f + __expf(-ig1));
      float os0 = 1.f / (1.f + __expf(-og0)), os1 = 1.f / (1.f + __expf(-og1));
      float cd0 = tanhf(cg0), cd1 = tanhf(cg1);
      c0r = fs0 * c0r + is0 * cd0;
      c1r = fs1 * c1r + is1 * cd1;
      float hn0 = os0 * tanhf(c0r), hn1 = os1 * tanhf(c1r);
      // publish h for step t+1 (critical-path stores only)
      const size_t hw = (size_t)(((t + 1) & 1) * HSLOT) + (size_t)(g * 16 + b0) * 512 + m * 16 + jj;
      u16 h0h = f2bf(hn0), h1h = f2bf(hn1);
      ushort2 sh; sh.x = h0h; sh.y = h1h;
      ushort2 sl; sl.x = f2bf(hn0 - bf2f(h0h)); sl.y = f2bf(hn1 - bf2f(h1h));
      *(ushort2*)(hbhi + hw) = sh;
      *(ushort2*)(hblo + hw) = sl;
      // release-store own flag: orders this wave's prior stores (vmcnt drain)
      if (l == 0)
        __hip_atomic_store(&gf[m], (unsigned)(t + 1), __ATOMIC_RELEASE,
                           __HIP_MEMORY_SCOPE_AGENT);
      // non-critical stores AFTER the flag
      float2 ho; ho.x = hn0; ho.y = hn1;
      *(float2*)(out + ((size_t)t * 64 + g * 8 + b0) * 512 + m * 16 + jj) = ho;
      if (t == T_STEPS - 1) {
        *(float2*)(out + (size_t)OUT_MAIN + (size_t)(g * 8 + b0) * 512 + m * 16 + jj) = ho;
        float2 co; co.x = c0r; co.y = c1r;
        *(float2*)(out + (size_t)OUT_MAIN + 32768 + (size_t)(g * 8 + b0) * 512 + m * 16 + jj) = co;
      }
      if (tl == Tc - 1) {
        float* cp = cws + (size_t)(g * 8 + b0) * 512 + m * 16 + jj;
        cp[0] = c0r; cp[1] = c1r;
      }
    }
  }
}

// ---------- host ----------
extern "C" void kernel_launch(void* const* d_in, const int* in_sizes, int n_in,
                              void* d_out, int out_size, void* d_ws, size_t ws_size,
                              hipStream_t stream) {
  const float* x  = (const float*)d_in[0];
  const float* h0 = (const float*)d_in[1];
  const float* c0 = (const float*)d_in[2];
  const float* W  = (const float*)d_in[3];
  const float* bs = (const float*)d_in[4];
  float* out = (float*)d_out;

  auto need = [](int tc) -> size_t {
    size_t s = 0;
    s += (size_t)tc * 524288;     // G fp32
    s += (size_t)tc * 131072;     // x hi+lo bf16
    s += 2 * (size_t)4194304;     // W^T hi+lo (full 1024 rows)
    s += 2 * (size_t)262144;      // hbuf hi+lo (2 parity slots)
    s += 131072;                  // c state
    s += 1024 + 8192;             // flags + alignment slack
    return s;
  };
  int Tc = 512;
  while (Tc > 2 && need(Tc) > ws_size) Tc >>= 1;

  char* p = (char*)d_ws;
  auto alloc = [&](size_t bytes) -> char* {
    char* r = p;
    p += (bytes + 255) & ~(size_t)255;
    return r;
  };
  float* Gbuf = (float*)alloc((size_t)Tc * 524288);
  u16* xhi  = (u16*)alloc((size_t)Tc * 65536);
  u16* xlo  = (u16*)alloc((size_t)Tc * 65536);
  u16* wthi = (u16*)alloc(4194304);
  u16* wtlo = (u16*)alloc(4194304);
  u16* hbhi = (u16*)alloc(262144);
  u16* hblo = (u16*)alloc(262144);
  float* cws = (float*)alloc(131072);
  unsigned* flags = (unsigned*)alloc(1024);

  hipLaunchKernelGGL(init_k, dim3(1024), dim3(256), 0, stream,
                     W, h0, c0, wthi, wtlo, hbhi, hblo, cws, flags);
  const int nch = 512 / Tc;
  for (int ck = 0; ck < nch; ++ck) {
    const float* xck = x + (size_t)ck * Tc * 64 * 512;
    int n4 = Tc * 64 * 512 / 4;
    hipLaunchKernelGGL(convx_k, dim3(1024), dim3(256), 0, stream, xck, xhi, xlo, n4);
    hipLaunchKernelGGL(gemm_k, dim3(Tc / 2 * 16), dim3(256), 0, stream,
                       xhi, xlo, wthi, wtlo, bs, Gbuf);
    hipLaunchKernelGGL(rec_k, dim3(256), dim3(256), 0, stream,
                       wthi, wtlo, Gbuf, hbhi, hblo, cws, out, flags, ck * Tc, Tc);
  }
}

// Round 5
// 2271.513 us; speedup vs baseline: 7.5033x; 7.5033x over previous
//
#include <hip/hip_runtime.h>
#include <cstdint>
#include <cstddef>

typedef unsigned short u16;
typedef unsigned long long u64;
typedef __attribute__((ext_vector_type(4))) float f32x4;
typedef __attribute__((ext_vector_type(8))) short s16x8;

#define T_STEPS 512
#define OUT_MAIN 16777216   // 512*64*512
#define HSLOT 65536         // u16 elements per parity slot (8 groups * 16 rows * 512)

// ---------- bf16 split helpers (bit-level RNE) ----------
static __device__ __forceinline__ u16 f2bf(float f) {
  unsigned u = __builtin_bit_cast(unsigned, f);
  unsigned r = u + 0x7FFFu + ((u >> 16) & 1u);
  return (u16)(r >> 16);
}
static __device__ __forceinline__ float bf2f(u16 h) {
  unsigned u = ((unsigned)h) << 16;
  return __builtin_bit_cast(float, u);
}

// ---------- init: full W transpose+split [2048][1024], h0/c0 staging, flags ----------
__global__ void init_k(const float* __restrict__ W, const float* __restrict__ h0,
                       const float* __restrict__ c0,
                       u16* __restrict__ wthi, u16* __restrict__ wtlo,
                       u16* __restrict__ hbhi, u16* __restrict__ hblo,
                       float* __restrict__ cws, unsigned* __restrict__ flags) {
  const int NW = 1024 * 2048;  // full W (Wx rows 0..511, Wh rows 512..1023)
  const int NH = 64 * 512;
  const int total = NW + 2 * NH + 256;
  for (int idx = blockIdx.x * blockDim.x + threadIdx.x; idx < total;
       idx += gridDim.x * blockDim.x) {
    if (idx < NW) {
      int k = idx >> 11;          // row of W (0..1023)
      int c = idx & 2047;         // gate column
      float wv = W[idx];
      u16 hi = f2bf(wv);
      wthi[(size_t)c * 1024 + k] = hi;
      wtlo[(size_t)c * 1024 + k] = f2bf(wv - bf2f(hi));
    } else if (idx < NW + NH) {
      int r = idx - NW; int b = r >> 9; int k = r & 511;
      int g = b >> 3, rr = b & 7;
      float v = h0[r];
      u16 hi = f2bf(v);
      int pos = (g * 16 + rr) * 512 + k;   // parity slot 0 (t=0 reads slot 0)
      hbhi[pos] = hi;
      hblo[pos] = f2bf(v - bf2f(hi));
    } else if (idx < NW + 2 * NH) {
      int r = idx - NW - NH;
      cws[r] = c0[r];
    } else {
      flags[idx - NW - 2 * NH] = 0u;   // re-armed every call (d_ws is re-poisoned)
    }
  }
}

// ---------- x chunk -> bf16 hi/lo ----------
__global__ void convx_k(const float* __restrict__ x, u16* __restrict__ hi,
                        u16* __restrict__ lo, int n4) {
  for (int i = blockIdx.x * blockDim.x + threadIdx.x; i < n4;
       i += gridDim.x * blockDim.x) {
    float4 v = ((const float4*)x)[i];
    ushort4 h, l2;
    h.x = f2bf(v.x); l2.x = f2bf(v.x - bf2f(h.x));
    h.y = f2bf(v.y); l2.y = f2bf(v.y - bf2f(h.y));
    h.z = f2bf(v.z); l2.z = f2bf(v.z - bf2f(h.z));
    h.w = f2bf(v.w); l2.w = f2bf(v.w - bf2f(h.w));
    ((ushort4*)hi)[i] = h;
    ((ushort4*)lo)[i] = l2;
  }
}

// ---------- G = x@Wx + b : 128x128 tile, 4 waves, 3-term bf16-split MFMA ----------
__global__ void __launch_bounds__(256, 2)
gemm_k(const u16* __restrict__ xhi, const u16* __restrict__ xlo,
       const u16* __restrict__ wthi, const u16* __restrict__ wtlo,
       const float* __restrict__ bias, float* __restrict__ Gout) {
  __shared__ u16 Ah[4096], Al[4096], Bh[4096], Bl[4096];   // [128][32] each
  const int tid = threadIdx.x;
  const int nb = blockIdx.x & 15;
  const int mb = blockIdx.x >> 4;
  const int w = tid >> 6, l = tid & 63;
  const int wm = w >> 1, wn = w & 1;
  const int lr = l & 15, lq = l >> 4;

  const int pos0 = tid, pos1 = tid + 256;
  const int row0 = pos0 >> 2, row1 = pos1 >> 2;
  const int cc = (tid & 3) * 8;
  const size_t aOff0 = (size_t)(mb * 128 + row0) * 512 + cc;
  const size_t aOff1 = (size_t)(mb * 128 + row1) * 512 + cc;
  const size_t bOff0 = (size_t)(nb * 128 + row0) * 1024 + cc;
  const size_t bOff1 = (size_t)(nb * 128 + row1) * 1024 + cc;

  float bv[4];
  #pragma unroll
  for (int n = 0; n < 4; ++n) bv[n] = bias[nb * 128 + wn * 64 + n * 16 + lr];

  f32x4 acc[4][4] = {};
  s16x8 rA0, rA1, rAl0, rAl1, rB0, rB1, rBl0, rBl1;
  rA0  = *(const s16x8*)(xhi  + aOff0);
  rA1  = *(const s16x8*)(xhi  + aOff1);
  rAl0 = *(const s16x8*)(xlo  + aOff0);
  rAl1 = *(const s16x8*)(xlo  + aOff1);
  rB0  = *(const s16x8*)(wthi + bOff0);
  rB1  = *(const s16x8*)(wthi + bOff1);
  rBl0 = *(const s16x8*)(wtlo + bOff0);
  rBl1 = *(const s16x8*)(wtlo + bOff1);

  for (int kt = 0; kt < 16; ++kt) {
    *(s16x8*)&Ah[pos0 * 8] = rA0;  *(s16x8*)&Ah[pos1 * 8] = rA1;
    *(s16x8*)&Al[pos0 * 8] = rAl0; *(s16x8*)&Al[pos1 * 8] = rAl1;
    *(s16x8*)&Bh[pos0 * 8] = rB0;  *(s16x8*)&Bh[pos1 * 8] = rB1;
    *(s16x8*)&Bl[pos0 * 8] = rBl0; *(s16x8*)&Bl[pos1 * 8] = rBl1;
    __syncthreads();
    if (kt < 15) {
      const int k0 = (kt + 1) * 32;
      rA0  = *(const s16x8*)(xhi  + aOff0 + k0);
      rA1  = *(const s16x8*)(xhi  + aOff1 + k0);
      rAl0 = *(const s16x8*)(xlo  + aOff0 + k0);
      rAl1 = *(const s16x8*)(xlo  + aOff1 + k0);
      rB0  = *(const s16x8*)(wthi + bOff0 + k0);
      rB1  = *(const s16x8*)(wthi + bOff1 + k0);
      rBl0 = *(const s16x8*)(wtlo + bOff0 + k0);
      rBl1 = *(const s16x8*)(wtlo + bOff1 + k0);
    }
    s16x8 fAh[4], fAl[4], fBh[4], fBl[4];
    #pragma unroll
    for (int mm = 0; mm < 4; ++mm) {
      const int rrow = wm * 64 + mm * 16 + lr;
      fAh[mm] = *(const s16x8*)&Ah[rrow * 32 + lq * 8];
      fAl[mm] = *(const s16x8*)&Al[rrow * 32 + lq * 8];
    }
    #pragma unroll
    for (int nn = 0; nn < 4; ++nn) {
      const int crow = wn * 64 + nn * 16 + lr;
      fBh[nn] = *(const s16x8*)&Bh[crow * 32 + lq * 8];
      fBl[nn] = *(const s16x8*)&Bl[crow * 32 + lq * 8];
    }
    #pragma unroll
    for (int mm = 0; mm < 4; ++mm)
      #pragma unroll
      for (int nn = 0; nn < 4; ++nn) {
        acc[mm][nn] = __builtin_amdgcn_mfma_f32_16x16x32_bf16(fAh[mm], fBh[nn], acc[mm][nn], 0, 0, 0);
        acc[mm][nn] = __builtin_amdgcn_mfma_f32_16x16x32_bf16(fAh[mm], fBl[nn], acc[mm][nn], 0, 0, 0);
        acc[mm][nn] = __builtin_amdgcn_mfma_f32_16x16x32_bf16(fAl[mm], fBh[nn], acc[mm][nn], 0, 0, 0);
      }
    __syncthreads();
  }
  #pragma unroll
  for (int mm = 0; mm < 4; ++mm)
    #pragma unroll
    for (int nn = 0; nn < 4; ++nn)
      #pragma unroll
      for (int i = 0; i < 4; ++i) {
        const int row = mb * 128 + wm * 64 + mm * 16 + lq * 4 + i;
        const int col = nb * 128 + wn * 64 + nn * 16 + lr;
        Gout[(size_t)row * 2048 + col] = acc[mm][nn][i] + bv[nn];
      }
}

// ---------- recurrence v3.1: relaxed sc1 message-passing (NO acquire/release ->
//            no buffer_inv/wbl2 L2 nukes), K-split waves, 2 barriers/step,
//            bounded spin (deadlock -> visible failure, not container death) ----------
__global__ void __launch_bounds__(256, 1)
rec_k(const u16* __restrict__ wthi, const u16* __restrict__ wtlo,
      const float* __restrict__ Gbuf,
      u16* __restrict__ hbhi, u16* __restrict__ hblo,
      float* __restrict__ cws, float* __restrict__ out,
      unsigned* __restrict__ flags, int t0, int Tc) {
  const int g = blockIdx.x & 7;        // group (XCD heuristic; perf-only)
  const int m = blockIdx.x >> 3;       // member 0..31: owns hidden units [16m,16m+16)
  const int tid = threadIdx.x;
  const int w = tid >> 6;              // wave = K-slice [w*128, w*128+128)
  const int l = tid & 63;
  const int lr = l & 15, lq = l >> 4;

  __shared__ float part[4][8][64];     // [wave][batch][gate*16+unit]

  // --- B fragments: wave w's K-slice of Wh, all 4 gates, bf16 hi/lo, in regs ---
  s16x8 bhi[4][4], blo[4][4];
  #pragma unroll
  for (int nt = 0; nt < 4; ++nt) {
    const size_t cb = (size_t)(nt * 512 + m * 16 + lr) * 1024 + 512 + w * 128 + lq * 8;
    #pragma unroll
    for (int kt = 0; kt < 4; ++kt) {
      bhi[kt][nt] = *(const s16x8*)(wthi + cb + kt * 32);
      blo[kt][nt] = *(const s16x8*)(wtlo + cb + kt * 32);
    }
  }

  const int b0 = l >> 3;               // wave-0 elementwise: batch
  const int jj = (l & 7) * 2;          // wave-0 elementwise: unit pair
  float c0r = 0.f, c1r = 0.f;
  if (w == 0) {
    const float* cp = cws + (size_t)(g * 8 + b0) * 512 + m * 16 + jj;
    c0r = cp[0]; c1r = cp[1];
  }
  unsigned* gf = flags + g * 32;
  // per-lane h-fragment base (u64 index within a parity slot), valid for lr<8
  const int fragBase = (g * 16 + lr) * 128 + w * 32 + lq * 2;

  for (int tl = 0; tl < Tc; ++tl) {
    const int t = t0 + tl;
    float2 gv0, gv1, gv2, gv3;
    if (w == 0) {
      // x-gate prefetch (race-free; L2/L3-cacheable plain loads)
      const float* gp = Gbuf + ((size_t)tl * 64 + g * 8 + b0) * 2048 + m * 16 + jj;
      gv0 = *(const float2*)(gp);
      gv1 = *(const float2*)(gp + 512);
      gv2 = *(const float2*)(gp + 1024);
      gv3 = *(const float2*)(gp + 1536);
      // poll 31 peer flags with RELAXED agent loads (sc1: coherent, no inv).
      // Bounded: legit waits are µs; 1<<27 iters ~ seconds. On trip, proceed
      // (wrong data but terminating) -> harness reports passed=false instead
      // of a wedged container.
      const unsigned tgt = (unsigned)t;
      int ok; unsigned spin = 0;
      do {
        unsigned v = 0xFFFFFFFFu;
        if (l < 32 && l != m)
          v = __hip_atomic_load(&gf[l], __ATOMIC_RELAXED, __HIP_MEMORY_SCOPE_AGENT);
        ok = __all((int)(v >= tgt));
        if (!ok) __builtin_amdgcn_s_sleep(2);
      } while (!ok && ++spin < (1u << 27));
    }
    __syncthreads();   // all waves gated on wave-0's poll

    // A fragments straight from the coherence point; pad rows (8..15) = 0 regs
    s16x8 ah[4], al[4];
    if (lr < 8) {
      const u64* sH = (const u64*)hbhi + (size_t)((t & 1) * (HSLOT / 4)) + fragBase;
      const u64* sL = (const u64*)hblo + (size_t)((t & 1) * (HSLOT / 4)) + fragBase;
      #pragma unroll
      for (int kt = 0; kt < 4; ++kt) {
        union { u64 q[2]; s16x8 v; } uh, ul;
        uh.q[0] = __hip_atomic_load((u64*)(sH + kt * 8),     __ATOMIC_RELAXED, __HIP_MEMORY_SCOPE_AGENT);
        uh.q[1] = __hip_atomic_load((u64*)(sH + kt * 8 + 1), __ATOMIC_RELAXED, __HIP_MEMORY_SCOPE_AGENT);
        ul.q[0] = __hip_atomic_load((u64*)(sL + kt * 8),     __ATOMIC_RELAXED, __HIP_MEMORY_SCOPE_AGENT);
        ul.q[1] = __hip_atomic_load((u64*)(sL + kt * 8 + 1), __ATOMIC_RELAXED, __HIP_MEMORY_SCOPE_AGENT);
        ah[kt] = uh.v; al[kt] = ul.v;
      }
    } else {
      #pragma unroll
      for (int kt = 0; kt < 4; ++kt) {
        ah[kt] = (s16x8)(short)0; al[kt] = (s16x8)(short)0;
      }
    }

    f32x4 acc[4] = {};
    #pragma unroll
    for (int kt = 0; kt < 4; ++kt)
      #pragma unroll
      for (int nt = 0; nt < 4; ++nt) {
        acc[nt] = __builtin_amdgcn_mfma_f32_16x16x32_bf16(ah[kt], bhi[kt][nt], acc[nt], 0, 0, 0);
        acc[nt] = __builtin_amdgcn_mfma_f32_16x16x32_bf16(ah[kt], blo[kt][nt], acc[nt], 0, 0, 0);
        acc[nt] = __builtin_amdgcn_mfma_f32_16x16x32_bf16(al[kt], bhi[kt][nt], acc[nt], 0, 0, 0);
      }
    // per-wave K-partial -> LDS (rows 0..7 real -> lanes 0..31)
    if (l < 32) {
      #pragma unroll
      for (int nt = 0; nt < 4; ++nt)
        #pragma unroll
        for (int i = 0; i < 4; ++i)
          part[w][lq * 4 + i][nt * 16 + lr] = acc[nt][i];
    }
    __syncthreads();

    if (w == 0) {
      float ga[4][2];
      #pragma unroll
      for (int gi = 0; gi < 4; ++gi) {
        float2 s0 = *(const float2*)&part[0][b0][gi * 16 + jj];
        float2 s1 = *(const float2*)&part[1][b0][gi * 16 + jj];
        float2 s2 = *(const float2*)&part[2][b0][gi * 16 + jj];
        float2 s3 = *(const float2*)&part[3][b0][gi * 16 + jj];
        ga[gi][0] = (s0.x + s1.x) + (s2.x + s3.x);
        ga[gi][1] = (s0.y + s1.y) + (s2.y + s3.y);
      }
      float fg0 = ga[0][0] + gv0.x, fg1 = ga[0][1] + gv0.y;
      float ig0 = ga[1][0] + gv1.x, ig1 = ga[1][1] + gv1.y;
      float cg0 = ga[2][0] + gv2.x, cg1 = ga[2][1] + gv2.y;
      float og0 = ga[3][0] + gv3.x, og1 = ga[3][1] + gv3.y;
      float fs0 = 1.f / (1.f + __expf(-fg0)), fs1 = 1.f / (1.f + __expf(-fg1));
      float is0 = 1.f / (1.f + __expf(-ig0)), is1 = 1.f / (1.f + __expf(-ig1));
      float os0 = 1.f / (1.f + __expf(-og0)), os1 = 1.f / (1.f + __expf(-og1));
      float cd0 = tanhf(cg0), cd1 = tanhf(cg1);
      c0r = fs0 * c0r + is0 * cd0;
      c1r = fs1 * c1r + is1 * cd1;
      float hn0 = os0 * tanhf(c0r), hn1 = os1 * tanhf(c1r);
      // publish h (relaxed sc1 dword stores -> coherence point)
      u16 h0h = f2bf(hn0), h1h = f2bf(hn1);
      u16 l0h = f2bf(hn0 - bf2f(h0h)), l1h = f2bf(hn1 - bf2f(h1h));
      const int pdw = ((t + 1) & 1) * (HSLOT / 2) + (g * 16 + b0) * 256 + (m * 16 + jj) / 2;
      unsigned hw2 = (unsigned)h0h | ((unsigned)h1h << 16);
      unsigned lw2 = (unsigned)l0h | ((unsigned)l1h << 16);
      __hip_atomic_store((unsigned*)hbhi + pdw, hw2, __ATOMIC_RELAXED, __HIP_MEMORY_SCOPE_AGENT);
      __hip_atomic_store((unsigned*)hblo + pdw, lw2, __ATOMIC_RELAXED, __HIP_MEMORY_SCOPE_AGENT);
      // manual release: drain the h stores, THEN raise the flag (relaxed)
      asm volatile("s_waitcnt vmcnt(0)" ::: "memory");
      if (l == 0)
        __hip_atomic_store(&gf[m], (unsigned)(t + 1), __ATOMIC_RELAXED, __HIP_MEMORY_SCOPE_AGENT);
      // non-critical stores AFTER the flag
      float2 ho; ho.x = hn0; ho.y = hn1;
      *(float2*)(out + ((size_t)t * 64 + g * 8 + b0) * 512 + m * 16 + jj) = ho;
      if (t == T_STEPS - 1) {
        *(float2*)(out + (size_t)OUT_MAIN + (size_t)(g * 8 + b0) * 512 + m * 16 + jj) = ho;
        float2 co; co.x = c0r; co.y = c1r;
        *(float2*)(out + (size_t)OUT_MAIN + 32768 + (size_t)(g * 8 + b0) * 512 + m * 16 + jj) = co;
      }
      if (tl == Tc - 1) {
        float* cp = cws + (size_t)(g * 8 + b0) * 512 + m * 16 + jj;
        cp[0] = c0r; cp[1] = c1r;
      }
    }
  }
}

// ---------- host ----------
extern "C" void kernel_launch(void* const* d_in, const int* in_sizes, int n_in,
                              void* d_out, int out_size, void* d_ws, size_t ws_size,
                              hipStream_t stream) {
  const float* x  = (const float*)d_in[0];
  const float* h0 = (const float*)d_in[1];
  const float* c0 = (const float*)d_in[2];
  const float* W  = (const float*)d_in[3];
  const float* bs = (const float*)d_in[4];
  float* out = (float*)d_out;

  auto need = [](int tc) -> size_t {
    size_t s = 0;
    s += (size_t)tc * 524288;     // G fp32
    s += (size_t)tc * 131072;     // x hi+lo bf16
    s += 2 * (size_t)4194304;     // W^T hi+lo (full 1024 rows)
    s += 2 * (size_t)262144;      // hbuf hi+lo (2 parity slots)
    s += 131072;                  // c state
    s += 1024 + 8192;             // flags + alignment slack
    return s;
  };
  int Tc = 512;
  while (Tc > 2 && need(Tc) > ws_size) Tc >>= 1;

  char* p = (char*)d_ws;
  auto alloc = [&](size_t bytes) -> char* {
    char* r = p;
    p += (bytes + 255) & ~(size_t)255;
    return r;
  };
  float* Gbuf = (float*)alloc((size_t)Tc * 524288);
  u16* xhi  = (u16*)alloc((size_t)Tc * 65536);
  u16* xlo  = (u16*)alloc((size_t)Tc * 65536);
  u16* wthi = (u16*)alloc(4194304);
  u16* wtlo = (u16*)alloc(4194304);
  u16* hbhi = (u16*)alloc(262144);
  u16* hblo = (u16*)alloc(262144);
  float* cws = (float*)alloc(131072);
  unsigned* flags = (unsigned*)alloc(1024);

  hipLaunchKernelGGL(init_k, dim3(1024), dim3(256), 0, stream,
                     W, h0, c0, wthi, wtlo, hbhi, hblo, cws, flags);
  const int nch = 512 / Tc;
  for (int ck = 0; ck < nch; ++ck) {
    const float* xck = x + (size_t)ck * Tc * 64 * 512;
    int n4 = Tc * 64 * 512 / 4;
    hipLaunchKernelGGL(convx_k, dim3(1024), dim3(256), 0, stream, xck, xhi, xlo, n4);
    hipLaunchKernelGGL(gemm_k, dim3(Tc / 2 * 16), dim3(256), 0, stream,
                       xhi, xlo, wthi, wtlo, bs, Gbuf);
    hipLaunchKernelGGL(rec_k, dim3(256), dim3(256), 0, stream,
                       wthi, wtlo, Gbuf, hbhi, hblo, cws, out, flags, ck * Tc, Tc);
  }
}